// Round 5
// baseline (187.100 us; speedup 1.0000x reference)
//
#include <hip/hip_runtime.h>
#include <hip/hip_bf16.h>

namespace {

typedef _Float16 v4h __attribute__((ext_vector_type(4)));
typedef __fp16   h2  __attribute__((ext_vector_type(2)));  // cvt_pkrtz return type
typedef float    v4f __attribute__((ext_vector_type(4)));

constexpr int B = 64, G = 512, D = 128, H = 8, KD = 16, NS = 20;
constexpr float NORM = 0.25f;        // 1/sqrt(KD)
constexpr float L2E  = 1.44269504088896f; // folded into Wq with NORM
constexpr float DTHR = 11.54f;       // defer-max threshold (8 nats in log2 dom.)
constexpr int KP = 20;               // Kl row pad (f16), 40 B rows
constexpr int VP = 524;              // Vt row pad (f16), 1048 B rows
constexpr int QP = 20;               // Ql row pad
constexpr int QCH = 256;             // queries per LDS-resident chunk

__device__ __forceinline__ v4f mfma16(v4h a, v4h b, v4f c) {
  // D = A(16xK16)*B(K16x16)+C. A: lane holds A[l&15][4*(l>>4)+i];
  // B: lane holds B[4*(l>>4)+i][l&15]; D: row=4*(l>>4)+i, col=l&15.
  return __builtin_amdgcn_mfma_f32_16x16x16f16(a, b, c, 0, 0, 0);
}
__device__ __forceinline__ v4h cvt4(float4 v) {
  h2 a = __builtin_amdgcn_cvt_pkrtz(v.x, v.y);
  h2 b = __builtin_amdgcn_cvt_pkrtz(v.z, v.w);
  return v4h{(_Float16)a[0], (_Float16)a[1], (_Float16)b[0], (_Float16)b[1]};
}

// One block (512 thr = 8 waves) per (b, head). blockIdx = hh*64 + b so the 8
// head-blocks of one batch share an XCD (round-robin %8 = b%8) -> h[b] L2-hot.
// Projections load A-fragments DIRECTLY from global (no LDS staging): lane
// reads row (tile*16+c), cols dc*16+4g..+3 as one float4 -> cvt -> MFMA.
template<int SEG>
__global__ __launch_bounds__(512, 4)
void attn_seg_kernel(const float* __restrict__ q, const float* __restrict__ hb,
                     const float* __restrict__ Wq, const float* __restrict__ Wk,
                     const float* __restrict__ Wv, float* __restrict__ heads)
{
  constexpr int Lq   = SEG == 0 ? 1 : SEG == 1 ? NS : G - 1 - NS;  // 1,20,491
  constexpr int QOFF = SEG == 0 ? 0 : SEG == 1 ? 1  : 1 + NS;
  constexpr int Ln   = SEG == 0 ? G - 1 - NS : SEG == 1 ? G - NS : G; // 491,492,512
  constexpr int NCH  = (Ln + 31) / 32;   // 32-key chunks
  constexpr int NQC  = (Lq + QCH - 1) / QCH;

  __shared__ alignas(16) struct {
    _Float16  Kl[512 * KP];         // K  [n][kd]            20480 B
    _Float16  Vt[16 * VP];          // V^T[kd][n]            16768 B
    _Float16  Ql[QCH * QP];         // Q  [q][kd]            10240 B
  } sm;                             // 47488 B total

  const int hh   = blockIdx.x >> 6;
  const int b    = blockIdx.x & 63;
  const int tid  = threadIdx.x;
  const int w    = tid >> 6;
  const int lane = tid & 63;
  const int g    = lane >> 4, c = lane & 15;

  // ---- W fragments in registers (B-operand layout) ----
  v4h wA[8];                        // waves 0-3: Wk, waves 4-7: Wv
  v4h wQ[8];                        // waves 0-3 only
  {
    const float* Wt = (w < 4) ? Wk : Wv;
    #pragma unroll
    for (int dc = 0; dc < 8; ++dc)
      #pragma unroll
      for (int bb = 0; bb < 4; ++bb)
        wA[dc][bb] = (_Float16)Wt[((size_t)hh * D + dc * 16 + 4 * g + bb) * KD + c];
    if (w < 4) {
      #pragma unroll
      for (int dc = 0; dc < 8; ++dc)
        #pragma unroll
        for (int bb = 0; bb < 4; ++bb)
          wQ[dc][bb] = (_Float16)(Wq[((size_t)hh * D + dc * 16 + 4 * g + bb) * KD + c]
                                  * (NORM * L2E));
    }
  }

  // ---- Phase B: K/V projection, wave-owned 16-row tiles, no staging ----
  for (int t = (w & 3); t < 32; t += 4) {
    int nn = t * 16 + c; if (nn > Ln - 1) nn = Ln - 1;   // clamp: dup row, masked later
    int hr;
    if (SEG == 0)      hr = nn + 1 + NS;
    else if (SEG == 1) hr = (nn == 0) ? 0 : nn + NS;
    else               hr = nn;
    const float4* hrow = (const float4*)(hb + ((size_t)b * G + hr) * D);
    v4f acc = {0.f, 0.f, 0.f, 0.f};
    #pragma unroll
    for (int dc = 0; dc < 8; ++dc)
      acc = mfma16(cvt4(hrow[dc * 4 + g]), wA[dc], acc);
    if (w < 4) {                     // D: tile row n = 4g+r, col kd = c
      #pragma unroll
      for (int r = 0; r < 4; ++r)
        sm.Kl[(t * 16 + 4 * g + r) * KP + c] = (_Float16)acc[r];
    } else {
      v4h vv = {(_Float16)acc[0], (_Float16)acc[1], (_Float16)acc[2], (_Float16)acc[3]};
      *(v4h*)(sm.Vt + c * VP + t * 16 + 4 * g) = vv;
    }
  }
  __syncthreads();

  // ---- per Q-chunk: project Q (direct loads), then attention ----
  for (int qc = 0; qc < NQC; ++qc) {
    const int qbase = qc * QCH;
    const int qcnt  = (Lq - qbase < QCH) ? (Lq - qbase) : QCH;
    const int nqt   = (qcnt + 15) / 16;
    if (w < 4) {
      for (int t2 = w; t2 < nqt; t2 += 4) {
        int qs = qbase + t2 * 16 + c; if (qs > Lq - 1) qs = Lq - 1;
        const float4* qrow = (const float4*)(q + ((size_t)b * G + QOFF + qs) * D);
        v4f acc = {0.f, 0.f, 0.f, 0.f};
        #pragma unroll
        for (int dc = 0; dc < 8; ++dc)
          acc = mfma16(cvt4(qrow[dc * 4 + g]), wQ[dc], acc);
        #pragma unroll
        for (int r = 0; r < 4; ++r)
          sm.Ql[(t2 * 16 + 4 * g + r) * QP + c] = (_Float16)acc[r];
      }
    }
    __syncthreads();

    // ---- attention: tiles of 16 queries, strided over 8 waves ----
    for (int tt = w; tt < nqt; tt += 8) {
      const v4h qf = *(const v4h*)(sm.Ql + (tt * 16 + c) * QP + 4 * g);
      const _Float16* Kb = sm.Kl + c * KP + 4 * g;
      const _Float16* Vb = sm.Vt + c * VP + 4 * g;
      float m = 0.f;                  // running max (log2 dom.), folded into mc
      v4f mc   = {0.f, 0.f, 0.f, 0.f};  // C-operand = -m (per-query splat)
      v4f o    = {0.f, 0.f, 0.f, 0.f};  // O^T: row kd=4g+r, col q=c
      v4f lacc = {0.f, 0.f, 0.f, 0.f};  // ones-MFMA column sums (replicated)
      const v4h ones = {(_Float16)1.f, (_Float16)1.f, (_Float16)1.f, (_Float16)1.f};
      #pragma unroll
      for (int ch = 0; ch < NCH; ++ch) {
        const int nb = ch * 32;
        v4f s0 = mfma16(*(const v4h*)(Kb + nb * KP), qf, mc);        // S-m: n=nb+4g+r
        v4f s1 = mfma16(*(const v4h*)(Kb + (nb + 16) * KP), qf, mc); // n=nb+16+4g+r
        if constexpr ((Ln & 31) != 0) {
          if (ch == NCH - 1) {
            #pragma unroll
            for (int r = 0; r < 4; ++r) {
              if (nb + 4 * g + r >= Ln)      s0[r] = -1e30f;
              if (nb + 16 + 4 * g + r >= Ln) s1[r] = -1e30f;
            }
          }
        }
        const float ma = fmaxf(fmaxf(s0[0], s0[1]), s0[2]);   // max3-fusable triples
        const float mb = fmaxf(fmaxf(s0[3], s1[0]), s1[1]);
        const float mz = fmaxf(fmaxf(s1[2], s1[3]), ma);
        const float mx = fmaxf(mb, mz);
        v4h p0, p1;
        if (__builtin_expect(__all(mx <= DTHR), 1)) {  // common: no rescale, no subs
          h2 e01 = __builtin_amdgcn_cvt_pkrtz(__builtin_amdgcn_exp2f(s0[0]),
                                              __builtin_amdgcn_exp2f(s0[1]));
          h2 e23 = __builtin_amdgcn_cvt_pkrtz(__builtin_amdgcn_exp2f(s0[2]),
                                              __builtin_amdgcn_exp2f(s0[3]));
          h2 e45 = __builtin_amdgcn_cvt_pkrtz(__builtin_amdgcn_exp2f(s1[0]),
                                              __builtin_amdgcn_exp2f(s1[1]));
          h2 e67 = __builtin_amdgcn_cvt_pkrtz(__builtin_amdgcn_exp2f(s1[2]),
                                              __builtin_amdgcn_exp2f(s1[3]));
          p0 = {(_Float16)e01[0], (_Float16)e01[1], (_Float16)e23[0], (_Float16)e23[1]};
          p1 = {(_Float16)e45[0], (_Float16)e45[1], (_Float16)e67[0], (_Float16)e67[1]};
        } else {                       // rare: max grew beyond defer threshold
          float d = fmaxf(mx, __shfl_xor(mx, 16));
          d = fmaxf(d, __shfl_xor(d, 32));
          d = fmaxf(d, 0.f);           // per-query growth (never decrease m)
          const float sc = __builtin_amdgcn_exp2f(-d);
          o *= sc; lacc *= sc;
          m += d;
          mc = {-m, -m, -m, -m};
          h2 e01 = __builtin_amdgcn_cvt_pkrtz(__builtin_amdgcn_exp2f(s0[0] - d),
                                              __builtin_amdgcn_exp2f(s0[1] - d));
          h2 e23 = __builtin_amdgcn_cvt_pkrtz(__builtin_amdgcn_exp2f(s0[2] - d),
                                              __builtin_amdgcn_exp2f(s0[3] - d));
          h2 e45 = __builtin_amdgcn_cvt_pkrtz(__builtin_amdgcn_exp2f(s1[0] - d),
                                              __builtin_amdgcn_exp2f(s1[1] - d));
          h2 e67 = __builtin_amdgcn_cvt_pkrtz(__builtin_amdgcn_exp2f(s1[2] - d),
                                              __builtin_amdgcn_exp2f(s1[3] - d));
          p0 = {(_Float16)e01[0], (_Float16)e01[1], (_Float16)e23[0], (_Float16)e23[1]};
          p1 = {(_Float16)e45[0], (_Float16)e45[1], (_Float16)e67[0], (_Float16)e67[1]};
        }
        o = mfma16(*(const v4h*)(Vb + nb), p0, o);        // O^T += V^T * P^T
        o = mfma16(*(const v4h*)(Vb + nb + 16), p1, o);
        lacc = mfma16(ones, p0, lacc);
        lacc = mfma16(ones, p1, lacc);
      }
      const float inv = 1.0f / lacc[0]; // column sum replicated across rows
      const int qloc = qbase + tt * 16 + c;   // lane's query = c, kd block = 4g
      if (qloc < Lq) {
        float4 val = {o[0] * inv, o[1] * inv, o[2] * inv, o[3] * inv};
        *(float4*)(heads + ((size_t)b * G + QOFF + qloc) * 128 + hh * 16 + 4 * g) = val;
      }
    }
    __syncthreads();
  }
}

// MFMA output projection, in place: row (b,g) of `data` holds heads[h*16+k]
// (128 values); out[b,g,e] = sum_k heads[k] * Wout[k][e]. 64 rows per block,
// 4 waves; Wout staged transposed [e][k] so B-fragments are v4h reads.
__global__ __launch_bounds__(256)
void out_proj_kernel(float* __restrict__ data, const float* __restrict__ Wout)
{
  __shared__ _Float16 WlT[128 * 132];  // [e][k], 33792 B
  __shared__ _Float16 Ah [64 * 132];   // [row][k], 16896 B
  const int tid  = threadIdx.x;
  const int lane = tid & 63, w = tid >> 6;
  const int g = lane >> 4, c = lane & 15;
  const size_t rowbase = (size_t)blockIdx.x * 64;

  #pragma unroll
  for (int i = 0; i < 16; ++i) {       // stage Wout^T (whole 128x128)
    int idx = tid + i * 256;           // 4096 float4
    int k = idx >> 5, c4 = (idx & 31) * 4;
    float4 v = ((const float4*)Wout)[idx];
    WlT[(c4 + 0) * 132 + k] = (_Float16)v.x;
    WlT[(c4 + 1) * 132 + k] = (_Float16)v.y;
    WlT[(c4 + 2) * 132 + k] = (_Float16)v.z;
    WlT[(c4 + 3) * 132 + k] = (_Float16)v.w;
  }
  #pragma unroll
  for (int i = 0; i < 8; ++i) {        // stage 64 A rows as f16
    int idx = tid + i * 256;           // 2048 float4
    int r = idx >> 5, c4 = (idx & 31) * 4;
    float4 v = ((const float4*)(data + rowbase * 128))[idx];
    *(v4h*)(Ah + r * 132 + c4) = cvt4(v);
  }
  __syncthreads();

  v4h af[8];                            // A-fragments: row c of wave's 16-tile
  #pragma unroll
  for (int dc = 0; dc < 8; ++dc)
    af[dc] = *(const v4h*)(Ah + (w * 16 + c) * 132 + dc * 16 + 4 * g);
  #pragma unroll
  for (int ct = 0; ct < 8; ++ct) {
    v4f acc = {0.f, 0.f, 0.f, 0.f};
    #pragma unroll
    for (int dc = 0; dc < 8; ++dc) {
      const v4h bf = *(const v4h*)(WlT + (ct * 16 + c) * 132 + dc * 16 + 4 * g);
      acc = mfma16(af[dc], bf, acc);
    }
    #pragma unroll
    for (int r = 0; r < 4; ++r)        // D: row=4g+r (tile row), col=c
      data[(rowbase + w * 16 + 4 * g + r) * 128 + ct * 16 + c] = acc[r];
  }
}

} // namespace

extern "C" void kernel_launch(void* const* d_in, const int* in_sizes, int n_in,
                              void* d_out, int out_size, void* d_ws, size_t ws_size,
                              hipStream_t stream) {
  const float* q    = (const float*)d_in[0];
  const float* h    = (const float*)d_in[1];
  const float* Wqd  = (const float*)d_in[2];
  const float* Wkc  = (const float*)d_in[3];
  const float* Wvc  = (const float*)d_in[4];
  const float* Wqs  = (const float*)d_in[5];
  const float* Wko  = (const float*)d_in[6];
  const float* Wvo  = (const float*)d_in[7];
  const float* Wqc  = (const float*)d_in[8];
  const float* Wka  = (const float*)d_in[9];
  const float* Wva  = (const float*)d_in[10];
  const float* Wout = (const float*)d_in[11];
  float* out = (float*)d_out;  // heads buffer, then transformed in place

  attn_seg_kernel<0><<<B * H, 512, 0, stream>>>(q, h, Wqd, Wkc, Wvc, out);
  attn_seg_kernel<1><<<B * H, 512, 0, stream>>>(q, h, Wqs, Wko, Wvo, out);
  attn_seg_kernel<2><<<B * H, 512, 0, stream>>>(q, h, Wqc, Wka, Wva, out);
  out_proj_kernel<<<G * B / 64, 256, 0, stream>>>(out, Wout);
}

// Round 6
// 70.635 us; speedup vs baseline: 2.6488x; 2.6488x over previous
//
#include <hip/hip_runtime.h>
#include <hip/hip_bf16.h>

namespace {

typedef _Float16 v4h __attribute__((ext_vector_type(4)));
typedef __fp16   h2  __attribute__((ext_vector_type(2)));  // cvt_pkrtz return type
typedef float    v4f __attribute__((ext_vector_type(4)));

constexpr int B = 64, G = 512, D = 128, H = 8, KD = 16, NS = 20;
constexpr float NORM = 0.25f;        // 1/sqrt(KD)
constexpr float L2E  = 1.44269504088896f; // folded into Wq with NORM
constexpr float DTHR = 11.54f;       // defer-max threshold (8 nats, log2 dom.)
constexpr int KP = 20;               // Kl row pad (f16), 40 B rows
constexpr int VP = 524;              // Vt row pad (f16), 1048 B rows
constexpr int QP = 20;               // Ql row pad
constexpr int QCH = 256;             // queries per LDS-resident chunk

__device__ __forceinline__ v4f mfma16(v4h a, v4h b, v4f c) {
  // D = A(16xK16)*B(K16x16)+C. A: lane holds A[l&15][4*(l>>4)+i];
  // B: lane holds B[4*(l>>4)+i][l&15]; D: row=4*(l>>4)+i, col=l&15.
  return __builtin_amdgcn_mfma_f32_16x16x16f16(a, b, c, 0, 0, 0);
}
__device__ __forceinline__ v4h cvt4(float4 v) {
  h2 a = __builtin_amdgcn_cvt_pkrtz(v.x, v.y);
  h2 b = __builtin_amdgcn_cvt_pkrtz(v.z, v.w);
  return v4h{(_Float16)a[0], (_Float16)a[1], (_Float16)b[0], (_Float16)b[1]};
}

struct SM {                          // 63,872 B total
  char      ht[16384];               // 64x128 f16 staging, XOR-swizzled; also scr
  _Float16  Kl[512 * KP];            // K  [n][kd]  20480 B
  _Float16  Vt[16 * VP];             // V^T[kd][n]  16768 B
  _Float16  Ql[QCH * QP];            // Q  [q][kd]  10240 B
};

// online-softmax for one 16q x 32k chunk; s0/s1 arrive as S - m (mc folded).
__device__ __forceinline__ void sm_chunk(v4f s0, v4f s1, float& m, v4f& mc,
                                         v4f& o, v4f& la, v4h& p0, v4h& p1) {
  const float ma = fmaxf(fmaxf(s0[0], s0[1]), s0[2]);    // max3-fusable triples
  const float mb = fmaxf(fmaxf(s0[3], s1[0]), s1[1]);
  const float mz = fmaxf(fmaxf(s1[2], s1[3]), ma);
  const float mx = fmaxf(mb, mz);
  if (__builtin_expect(!__all(mx <= DTHR), 0)) {  // rare: max grew > threshold
    float d = fmaxf(mx, __shfl_xor(mx, 16));
    d = fmaxf(d, __shfl_xor(d, 32));
    d = fmaxf(d, 0.f);
    const float sc = __builtin_amdgcn_exp2f(-d);
    o *= sc; la *= sc; m += d;
    mc[0] = -m; mc[1] = -m; mc[2] = -m; mc[3] = -m;
    const v4f dv = {d, d, d, d};
    s0 -= dv; s1 -= dv;
  }
  h2 e01 = __builtin_amdgcn_cvt_pkrtz(__builtin_amdgcn_exp2f(s0[0]),
                                      __builtin_amdgcn_exp2f(s0[1]));
  h2 e23 = __builtin_amdgcn_cvt_pkrtz(__builtin_amdgcn_exp2f(s0[2]),
                                      __builtin_amdgcn_exp2f(s0[3]));
  h2 e45 = __builtin_amdgcn_cvt_pkrtz(__builtin_amdgcn_exp2f(s1[0]),
                                      __builtin_amdgcn_exp2f(s1[1]));
  h2 e67 = __builtin_amdgcn_cvt_pkrtz(__builtin_amdgcn_exp2f(s1[2]),
                                      __builtin_amdgcn_exp2f(s1[3]));
  p0 = {(_Float16)e01[0], (_Float16)e01[1], (_Float16)e23[0], (_Float16)e23[1]};
  p1 = {(_Float16)e45[0], (_Float16)e45[1], (_Float16)e67[0], (_Float16)e67[1]};
}

// One block-worth of work for segment SEG at logical block id bid = hh*64+b.
template<int SEG>
__device__ __forceinline__ void seg_body(
    int bid, const float* __restrict__ q, const float* __restrict__ hb,
    const float* __restrict__ Wq, const float* __restrict__ Wk,
    const float* __restrict__ Wv, float* __restrict__ heads, SM& sm)
{
  constexpr int Lq   = SEG == 0 ? 1 : SEG == 1 ? NS : G - 1 - NS;  // 1,20,491
  constexpr int QOFF = SEG == 0 ? 0 : SEG == 1 ? 1  : 1 + NS;
  constexpr int Ln   = SEG == 0 ? G - 1 - NS : SEG == 1 ? G - NS : G; // 491,492,512
  constexpr int NCH  = (Ln + 31) / 32;   // 32-key chunks (16)
  constexpr int NQC  = (Lq + QCH - 1) / QCH;

  const int hh   = bid >> 6;
  const int b    = bid & 63;
  const int tid  = threadIdx.x;
  const int w    = tid >> 6;
  const int lane = tid & 63;
  const int g    = lane >> 4, c = lane & 15;

  // ---- W fragments in registers (B-operand layout) ----
  v4h wA[8];                        // waves 0-3: Wk, waves 4-7: Wv
  v4h wQ[8];                        // waves 0-3 only
  {
    const float* Wt = (w < 4) ? Wk : Wv;
    #pragma unroll
    for (int dc = 0; dc < 8; ++dc)
      #pragma unroll
      for (int bb = 0; bb < 4; ++bb)
        wA[dc][bb] = (_Float16)Wt[((size_t)hh * D + dc * 16 + 4 * g + bb) * KD + c];
    if (w < 4) {
      #pragma unroll
      for (int dc = 0; dc < 8; ++dc)
        #pragma unroll
        for (int bb = 0; bb < 4; ++bb)
          wQ[dc][bb] = (_Float16)(Wq[((size_t)hh * D + dc * 16 + 4 * g + bb) * KD + c]
                                  * (NORM * L2E));
    }
  }

  // ---- Phase B: K/V projection via coalesced LDS staging ----
  const int sb = w & 3;
  for (int t = 0; t < 8; ++t) {
    const int base = t * 64;
    #pragma unroll
    for (int i = 0; i < 4; ++i) {    // stage 64 h rows -> f16 swizzled
      int idx = tid + i * 512, r = idx >> 5, jj = idx & 31;
      int n = base + r;
      int nn = n < Ln ? n : Ln - 1;  // clamp: dup rows masked in attention
      int hr;
      if (SEG == 0)      hr = nn + 1 + NS;
      else if (SEG == 1) hr = (nn == 0) ? 0 : nn + NS;
      else               hr = nn;
      float4 v = ((const float4*)(hb + ((size_t)b * G + hr) * D))[jj];
      *(v4h*)(sm.ht + r * 256 + ((8 * jj) ^ ((r & 7) << 4))) = cvt4(v);
    }
    __syncthreads();
    v4f acc = {0.f, 0.f, 0.f, 0.f};
    #pragma unroll
    for (int dc = 0; dc < 8; ++dc) {
      const v4h a = *(const v4h*)(sm.ht + (sb * 16 + c) * 256 +
                                  ((32 * dc + 8 * g) ^ ((c & 7) << 4)));
      acc = mfma16(a, wA[dc], acc);
    }
    if (w < 4) {                     // D: row n = 4g+r (in 16-tile), col kd = c
      #pragma unroll
      for (int r = 0; r < 4; ++r)
        sm.Kl[(base + sb * 16 + 4 * g + r) * KP + c] = (_Float16)acc[r];
    } else {
      v4h vv = {(_Float16)acc[0], (_Float16)acc[1], (_Float16)acc[2], (_Float16)acc[3]};
      *(v4h*)(sm.Vt + c * VP + base + sb * 16 + 4 * g) = vv;
    }
    __syncthreads();
  }

  // ---- per Q-chunk: stage+project Q, then attention ----
  for (int qc = 0; qc < NQC; ++qc) {
    const int qbase = qc * QCH;
    const int qcnt  = (Lq - qbase < QCH) ? (Lq - qbase) : QCH;
    const int nst   = (qcnt + 63) / 64;
    for (int st = 0; st < nst; ++st) {
      #pragma unroll
      for (int i = 0; i < 4; ++i) {  // stage 64 q rows
        int idx = tid + i * 512, r = idx >> 5, jj = idx & 31;
        int qs = qbase + st * 64 + r;
        int gq = QOFF + (qs < Lq ? qs : Lq - 1);
        float4 v = ((const float4*)(q + ((size_t)b * G + gq) * D))[jj];
        *(v4h*)(sm.ht + r * 256 + ((8 * jj) ^ ((r & 7) << 4))) = cvt4(v);
      }
      __syncthreads();
      if (w < 4) {
        v4f acc = {0.f, 0.f, 0.f, 0.f};
        #pragma unroll
        for (int dc = 0; dc < 8; ++dc) {
          const v4h a = *(const v4h*)(sm.ht + (w * 16 + c) * 256 +
                                      ((32 * dc + 8 * g) ^ ((c & 7) << 4)));
          acc = mfma16(a, wQ[dc], acc);
        }
        #pragma unroll
        for (int r = 0; r < 4; ++r)
          sm.Ql[(st * 64 + w * 16 + 4 * g + r) * QP + c] = (_Float16)acc[r];
      }
      __syncthreads();
    }

    // ---- attention: PAIRS of 16-query tiles per wave (2 indep chains) ----
    const int nqt = (qcnt + 15) / 16;
    for (int t0 = w; t0 < nqt; t0 += 16) {
      const int tB = t0 + 8;
      const bool hasB = tB < nqt;
      const v4h qfA = *(const v4h*)(sm.Ql + (t0 * 16 + c) * QP + 4 * g);
      const v4h qfB = hasB ? *(const v4h*)(sm.Ql + (tB * 16 + c) * QP + 4 * g) : qfA;
      const _Float16* Kb = sm.Kl + c * KP + 4 * g;
      const _Float16* Vb = sm.Vt + c * VP + 4 * g;
      float mA = 0.f, mB = 0.f;
      v4f mcA = {0.f,0.f,0.f,0.f}, mcB = {0.f,0.f,0.f,0.f};
      v4f oA  = {0.f,0.f,0.f,0.f}, oB  = {0.f,0.f,0.f,0.f};
      v4f laA = {0.f,0.f,0.f,0.f}, laB = {0.f,0.f,0.f,0.f};
      const v4h ones = {(_Float16)1.f, (_Float16)1.f, (_Float16)1.f, (_Float16)1.f};
      #pragma unroll
      for (int ch = 0; ch < NCH; ++ch) {
        const int nb = ch * 32;
        const v4h k0 = *(const v4h*)(Kb + nb * KP);
        const v4h k1 = *(const v4h*)(Kb + (nb + 16) * KP);
        const v4h v0 = *(const v4h*)(Vb + nb);
        const v4h v1 = *(const v4h*)(Vb + nb + 16);
        v4f s0A = mfma16(k0, qfA, mcA);   // (S-m): n=nb+4g+r, q=c
        v4f s1A = mfma16(k1, qfA, mcA);
        v4f s0B = mfma16(k0, qfB, mcB);
        v4f s1B = mfma16(k1, qfB, mcB);
        if constexpr ((Ln & 31) != 0) {   // tail-key mask (SEG0/1 only)
          if (ch == NCH - 1) {
            #pragma unroll
            for (int r = 0; r < 4; ++r) {
              if (nb + 4 * g + r >= Ln)      { s0A[r] = -1e30f; s0B[r] = -1e30f; }
              if (nb + 16 + 4 * g + r >= Ln) { s1A[r] = -1e30f; s1B[r] = -1e30f; }
            }
          }
        }
        v4h p0, p1;
        sm_chunk(s0A, s1A, mA, mcA, oA, laA, p0, p1);
        oA  = mfma16(v0, p0, oA);
        oA  = mfma16(v1, p1, oA);
        laA = mfma16(ones, p0, laA);
        laA = mfma16(ones, p1, laA);
        sm_chunk(s0B, s1B, mB, mcB, oB, laB, p0, p1);
        oB  = mfma16(v0, p0, oB);
        oB  = mfma16(v1, p1, oB);
        laB = mfma16(ones, p0, laB);
        laB = mfma16(ones, p1, laB);
      }
      // store: LDS-transpose per tile -> coalesced 64 B row chunks
      float* scr = (float*)(sm.ht + w * 1280);  // 16 x 20 f32, per-wave
      #pragma unroll
      for (int u = 0; u < 2; ++u) {
        if (u == 1 && !hasB) break;
        const v4f& o  = u ? oB : oA;
        const v4f& la = u ? laB : laA;
        const int  tt = u ? tB : t0;
        const float inv = 1.0f / la[0];  // colsum replicated across rows
        #pragma unroll
        for (int r = 0; r < 4; ++r) scr[c * 20 + 4 * g + r] = o[r] * inv;
        const int row = lane >> 2, c4 = lane & 3;  // wave-synchronous reuse
        float4 val = *(const float4*)(scr + row * 20 + 4 * c4);
        const int qloc = qbase + tt * 16 + row;
        if (qloc < Lq)
          *(float4*)(heads + ((size_t)b * G + QOFF + qloc) * 128 + hh * 16 + 4 * c4) = val;
      }
    }
    __syncthreads();
  }
}

// All three segments in one launch: SEG2 blocks first (longest), then SEG1,
// SEG0. Within each 512-range bid%8 = b%8, so every block touching h[b]
// lands on XCD b%8 -> h L2-hot across segments.
__global__ __launch_bounds__(512, 4)
void fused_attn(const float* __restrict__ q, const float* __restrict__ hb,
                const float* __restrict__ Wqd, const float* __restrict__ Wkc,
                const float* __restrict__ Wvc, const float* __restrict__ Wqs,
                const float* __restrict__ Wko, const float* __restrict__ Wvo,
                const float* __restrict__ Wqc, const float* __restrict__ Wka,
                const float* __restrict__ Wva, float* __restrict__ heads)
{
  __shared__ SM sm;
  const int bid = blockIdx.x;
  if (bid < 512)       seg_body<2>(bid,        q, hb, Wqc, Wka, Wva, heads, sm);
  else if (bid < 1024) seg_body<1>(bid - 512,  q, hb, Wqs, Wko, Wvo, heads, sm);
  else                 seg_body<0>(bid - 1024, q, hb, Wqd, Wkc, Wvc, heads, sm);
}

// MFMA output projection, in place: row (b,g) of `data` holds heads[h*16+k]
// (128 values); out[b,g,e] = sum_k heads[k] * Wout[k][e]. 64 rows per block,
// 4 waves; Wout staged transposed [e][k] so B-fragments are v4h reads.
__global__ __launch_bounds__(256)
void out_proj_kernel(float* __restrict__ data, const float* __restrict__ Wout)
{
  __shared__ _Float16 WlT[128 * 132];  // [e][k], 33792 B
  __shared__ _Float16 Ah [64 * 132];   // [row][k], 16896 B
  const int tid  = threadIdx.x;
  const int lane = tid & 63, w = tid >> 6;
  const int g = lane >> 4, c = lane & 15;
  const size_t rowbase = (size_t)blockIdx.x * 64;

  #pragma unroll
  for (int i = 0; i < 16; ++i) {       // stage Wout^T (whole 128x128)
    int idx = tid + i * 256;           // 4096 float4
    int k = idx >> 5, c4 = (idx & 31) * 4;
    float4 v = ((const float4*)Wout)[idx];
    WlT[(c4 + 0) * 132 + k] = (_Float16)v.x;
    WlT[(c4 + 1) * 132 + k] = (_Float16)v.y;
    WlT[(c4 + 2) * 132 + k] = (_Float16)v.z;
    WlT[(c4 + 3) * 132 + k] = (_Float16)v.w;
  }
  #pragma unroll
  for (int i = 0; i < 8; ++i) {        // stage 64 A rows as f16
    int idx = tid + i * 256;           // 2048 float4
    int r = idx >> 5, c4 = (idx & 31) * 4;
    float4 v = ((const float4*)(data + rowbase * 128))[idx];
    *(v4h*)(Ah + r * 132 + c4) = cvt4(v);
  }
  __syncthreads();

  v4h af[8];                            // A-fragments: row c of wave's 16-tile
  #pragma unroll
  for (int dc = 0; dc < 8; ++dc)
    af[dc] = *(const v4h*)(Ah + (w * 16 + c) * 132 + dc * 16 + 4 * g);
  #pragma unroll
  for (int ct = 0; ct < 8; ++ct) {
    v4f acc = {0.f, 0.f, 0.f, 0.f};
    #pragma unroll
    for (int dc = 0; dc < 8; ++dc) {
      const v4h bf = *(const v4h*)(WlT + (ct * 16 + c) * 132 + dc * 16 + 4 * g);
      acc = mfma16(af[dc], bf, acc);
    }
    #pragma unroll
    for (int r = 0; r < 4; ++r)        // D: row=4g+r (tile row), col=c
      data[(rowbase + w * 16 + 4 * g + r) * 128 + ct * 16 + c] = acc[r];
  }
}

} // namespace

extern "C" void kernel_launch(void* const* d_in, const int* in_sizes, int n_in,
                              void* d_out, int out_size, void* d_ws, size_t ws_size,
                              hipStream_t stream) {
  const float* q    = (const float*)d_in[0];
  const float* h    = (const float*)d_in[1];
  const float* Wqd  = (const float*)d_in[2];
  const float* Wkc  = (const float*)d_in[3];
  const float* Wvc  = (const float*)d_in[4];
  const float* Wqs  = (const float*)d_in[5];
  const float* Wko  = (const float*)d_in[6];
  const float* Wvo  = (const float*)d_in[7];
  const float* Wqc  = (const float*)d_in[8];
  const float* Wka  = (const float*)d_in[9];
  const float* Wva  = (const float*)d_in[10];
  const float* Wout = (const float*)d_in[11];
  float* out = (float*)d_out;  // heads buffer, then transformed in place

  fused_attn<<<3 * B * H, 512, 0, stream>>>(q, h, Wqd, Wkc, Wvc,
                                            Wqs, Wko, Wvo, Wqc, Wka, Wva, out);
  out_proj_kernel<<<G * B / 64, 256, 0, stream>>>(out, Wout);
}